// Round 1
// baseline (492.279 us; speedup 1.0000x reference)
//
#include <hip/hip_runtime.h>
#include <hip/hip_bf16.h>

#define NN 50000
#define NE 600000
#define BAG 16
#define EMB 128
#define HID 128
#define NC 10
#define NG 512
#define PAD_IDX 1

typedef __attribute__((ext_vector_type(8))) short v8s;
typedef __attribute__((ext_vector_type(4))) float v4f;

__device__ __forceinline__ float bflo(unsigned u) { return __uint_as_float(u << 16); }
__device__ __forceinline__ float bfhi(unsigned u) { return __uint_as_float(u & 0xffff0000u); }
__device__ __forceinline__ unsigned short f2bf(float f) {
    unsigned u = __float_as_uint(f);
    return (unsigned short)((u + 0x7fffu + ((u >> 16) & 1u)) >> 16);
}

// ---------- CSR build ----------
__global__ void k_count(const int* __restrict__ dst, int* __restrict__ counts) {
    int e = blockIdx.x * blockDim.x + threadIdx.x;
    if (e < NE) atomicAdd(&counts[dst[e]], 1);
}

__global__ void k_scan(const int* __restrict__ counts, int* __restrict__ row_ptr,
                       int* __restrict__ cursor) {
    __shared__ int buf[1024];
    __shared__ int carry_s;
    int tid = threadIdx.x;
    if (tid == 0) carry_s = 0;
    __syncthreads();
    for (int base = 0; base < NN; base += 1024) {
        int i = base + tid;
        int v = (i < NN) ? counts[i] : 0;
        buf[tid] = v;
        __syncthreads();
        for (int off = 1; off < 1024; off <<= 1) {
            int t = (tid >= off) ? buf[tid - off] : 0;
            __syncthreads();
            buf[tid] += t;
            __syncthreads();
        }
        int incl = buf[tid];
        int total = buf[1023];
        int carry = carry_s;
        if (i < NN) {
            int ex = carry + incl - v;
            row_ptr[i] = ex;
            cursor[i] = ex;
        }
        __syncthreads();
        if (tid == 0) carry_s = carry + total;
        __syncthreads();
    }
    if (tid == 0) row_ptr[NN] = carry_s;
}

__global__ void k_scatter(const int* __restrict__ src, const int* __restrict__ dst,
                          int* __restrict__ cursor, int* __restrict__ csr_src) {
    int e = blockIdx.x * blockDim.x + threadIdx.x;
    if (e < NE) {
        int p = atomicAdd(&cursor[dst[e]], 1);
        csr_src[p] = src[e];
    }
}

// ---------- embedding bag (mean, excluding PAD_IDX) -> bf16 x0 ----------
__global__ __launch_bounds__(256) void k_embed(const int* __restrict__ tokens,
                                               const float* __restrict__ table,
                                               unsigned short* __restrict__ x0) {
    int node = blockIdx.x * 4 + (threadIdx.x >> 6);
    int lane = threadIdx.x & 63;
    if (node >= NN) return;
    const int* tp = tokens + node * BAG;
    float ax = 0.f, ay = 0.f;
    int cnt = 0;
#pragma unroll
    for (int t = 0; t < BAG; t++) {
        int tok = tp[t];  // wave-uniform broadcast load
        if (tok != PAD_IDX) {
            float2 v = *(const float2*)(table + (size_t)tok * EMB + lane * 2);
            ax += v.x;
            ay += v.y;
            cnt++;
        }
    }
    float inv = 1.0f / (float)(cnt > 0 ? cnt : 1);
    unsigned lo = f2bf(ax * inv), hi = f2bf(ay * inv);
    *(unsigned*)(x0 + (size_t)node * EMB + lane * 2) = lo | (hi << 16);
}

// ---------- fp32 -> bf16 weight conversion ----------
__global__ void k_convw(const float* __restrict__ w1l, const float* __restrict__ w1r,
                        const float* __restrict__ w2l, const float* __restrict__ w2r,
                        unsigned short* __restrict__ wbf) {
    int i = blockIdx.x * blockDim.x + threadIdx.x;  // 0..16383
    wbf[i] = f2bf(w1l[i]);
    wbf[16384 + i] = f2bf(w1r[i]);
    wbf[32768 + i] = f2bf(w2l[i]);
    wbf[49152 + i] = f2bf(w2r[i]);
}

// ---------- neighbor mean aggregation (CSR gather), bf16 in/out, fp32 acc ----------
__global__ __launch_bounds__(256) void k_aggr(const unsigned short* __restrict__ x,
                                              const int* __restrict__ row_ptr,
                                              const int* __restrict__ csr_src,
                                              unsigned short* __restrict__ aggr) {
    int node = blockIdx.x * 4 + (threadIdx.x >> 6);
    int lane = threadIdx.x & 63;
    if (node >= NN) return;
    int s = row_ptr[node], e = row_ptr[node + 1];
    float ax = 0.f, ay = 0.f;
    for (int i = s; i < e; i++) {
        int src = csr_src[i];  // wave-uniform broadcast load
        unsigned v = *(const unsigned*)(x + (size_t)src * HID + lane * 2);
        ax += bflo(v);
        ay += bfhi(v);
    }
    int deg = e - s;
    float inv = 1.0f / (float)(deg > 0 ? deg : 1);
    unsigned lo = f2bf(ax * inv), hi = f2bf(ay * inv);
    *(unsigned*)(aggr + (size_t)node * HID + lane * 2) = lo | (hi << 16);
}

// ---------- fused SAGE linear: relu(aggr@wl^T + b + x@wr^T), MFMA bf16 ----------
// M-tile 128 nodes/block, N=128 outputs, K=256 (two K=128 halves: aggr|wl then x|wr)
__global__ __launch_bounds__(256) void k_sage(const unsigned short* __restrict__ xa,
                                              const unsigned short* __restrict__ xr,
                                              const unsigned short* __restrict__ wl,
                                              const unsigned short* __restrict__ wr,
                                              const float* __restrict__ bias,
                                              unsigned short* __restrict__ out) {
    __shared__ unsigned short As[128 * 32];
    __shared__ unsigned short Bs[128 * 32];
    int tid = threadIdx.x;
    int wave = tid >> 6, lane = tid & 63;
    int q = lane >> 4, l16 = lane & 15;
    int row0 = blockIdx.x * 128;

    v4f acc[2][8];
#pragma unroll
    for (int m = 0; m < 2; m++)
#pragma unroll
        for (int n = 0; n < 8; n++) acc[m][n] = (v4f){0.f, 0.f, 0.f, 0.f};

    for (int kc = 0; kc < 8; kc++) {
        const unsigned short* Ag = (kc < 4) ? xa : xr;
        const unsigned short* Bg = (kc < 4) ? wl : wr;
        int koff = (kc & 3) * 32;
#pragma unroll
        for (int it = 0; it < 2; it++) {
            int seg = tid + it * 256;  // 0..511 : 128 rows x 4 segments of 8 bf16
            int r = seg >> 2, sg = seg & 3;
            int gr = row0 + r;
            if (gr > NN - 1) gr = NN - 1;
            v8s a = *(const v8s*)(Ag + (size_t)gr * HID + koff + sg * 8);
            *(v8s*)(As + r * 32 + sg * 8) = a;
            v8s b = *(const v8s*)(Bg + (size_t)r * HID + koff + sg * 8);
            *(v8s*)(Bs + r * 32 + sg * 8) = b;
        }
        __syncthreads();
        v8s a0 = *(const v8s*)(As + (wave * 32 + l16) * 32 + q * 8);
        v8s a1 = *(const v8s*)(As + (wave * 32 + 16 + l16) * 32 + q * 8);
#pragma unroll
        for (int nt = 0; nt < 8; nt++) {
            v8s b = *(const v8s*)(Bs + (nt * 16 + l16) * 32 + q * 8);
            acc[0][nt] = __builtin_amdgcn_mfma_f32_16x16x32_bf16(a0, b, acc[0][nt], 0, 0, 0);
            acc[1][nt] = __builtin_amdgcn_mfma_f32_16x16x32_bf16(a1, b, acc[1][nt], 0, 0, 0);
        }
        __syncthreads();
    }
    // epilogue: C/D layout col=lane&15, row=quad*4+reg (m89-verified)
#pragma unroll
    for (int nt = 0; nt < 8; nt++) {
        int col = nt * 16 + l16;
        float bv = bias[col];
#pragma unroll
        for (int mt = 0; mt < 2; mt++) {
#pragma unroll
            for (int r = 0; r < 4; r++) {
                int row = row0 + wave * 32 + mt * 16 + q * 4 + r;
                if (row < NN) {
                    float v = acc[mt][nt][r] + bv;
                    v = v > 0.f ? v : 0.f;
                    out[(size_t)row * HID + col] = f2bf(v);
                }
            }
        }
    }
}

// ---------- global mean pool (batch sorted): run-length local acc, few atomics ----------
__global__ __launch_bounds__(128) void k_pool(const unsigned short* __restrict__ x2,
                                              const int* __restrict__ batch,
                                              float* __restrict__ gsum,
                                              float* __restrict__ gcnt) {
    int tid = threadIdx.x;
    int start = blockIdx.x * 128;
    int end = start + 128;
    if (end > NN) end = NN;
    int cur = batch[start];
    float acc = 0.f;
    int cnt = 0;
    for (int n = start; n < end; n++) {
        int b = batch[n];  // uniform across block
        if (b != cur) {
            atomicAdd(&gsum[cur * HID + tid], acc);
            if (tid == 0) atomicAdd(&gcnt[cur], (float)cnt);
            acc = 0.f;
            cnt = 0;
            cur = b;
        }
        acc += __uint_as_float(((unsigned)x2[(size_t)n * HID + tid]) << 16);
        cnt++;
    }
    atomicAdd(&gsum[cur * HID + tid], acc);
    if (tid == 0) atomicAdd(&gcnt[cur], (float)cnt);
}

// ---------- final classifier: out = (gsum/gcnt) @ w_out^T + b_out ----------
__global__ __launch_bounds__(128) void k_final(const float* __restrict__ gsum,
                                               const float* __restrict__ gcnt,
                                               const float* __restrict__ w_out,
                                               const float* __restrict__ b_out,
                                               float* __restrict__ out) {
    __shared__ float mean[HID];
    int g = blockIdx.x, tid = threadIdx.x;
    float c = gcnt[g];
    float ic = 1.0f / fmaxf(c, 1.0f);
    mean[tid] = gsum[g * HID + tid] * ic;
    __syncthreads();
    if (tid < NC) {
        float s = b_out[tid];
#pragma unroll 16
        for (int d = 0; d < HID; d++) s += mean[d] * w_out[tid * HID + d];
        out[g * NC + tid] = s;
    }
}

extern "C" void kernel_launch(void* const* d_in, const int* in_sizes, int n_in,
                              void* d_out, int out_size, void* d_ws, size_t ws_size,
                              hipStream_t stream) {
    const int* x_tokens = (const int*)d_in[0];
    const int* edge = (const int*)d_in[1];
    const int* batch = (const int*)d_in[2];
    const float* emb_table = (const float*)d_in[3];
    const float* w1l = (const float*)d_in[4];
    const float* b1 = (const float*)d_in[5];
    const float* w1r = (const float*)d_in[6];
    const float* w2l = (const float*)d_in[7];
    const float* b2 = (const float*)d_in[8];
    const float* w2r = (const float*)d_in[9];
    const float* w_out = (const float*)d_in[10];
    const float* b_out = (const float*)d_in[11];
    float* out = (float*)d_out;

    char* ws = (char*)d_ws;
    size_t off = 0;
    auto alloc = [&](size_t bytes) {
        void* p = ws + off;
        off += (bytes + 255) & ~(size_t)255;
        return p;
    };
    int* counts = (int*)alloc(NN * 4);
    int* row_ptr = (int*)alloc((NN + 1) * 4);
    int* cursor = (int*)alloc(NN * 4);
    int* csr_src = (int*)alloc(NE * 4);
    unsigned short* wbf = (unsigned short*)alloc(4 * HID * EMB * 2);
    float* gsum = (float*)alloc(NG * HID * 4);
    float* gcnt = (float*)alloc(NG * 4);
    unsigned short* x0 = (unsigned short*)alloc((size_t)NN * EMB * 2);
    unsigned short* x1 = (unsigned short*)alloc((size_t)NN * HID * 2);
    unsigned short* aggr = (unsigned short*)alloc((size_t)NN * HID * 2);
    unsigned short* x2 = x0;  // x0 dead after layer-1 GEMM; reuse

    hipMemsetAsync(counts, 0, NN * 4, stream);
    hipMemsetAsync(gsum, 0, NG * HID * 4, stream);
    hipMemsetAsync(gcnt, 0, NG * 4, stream);

    const int* srcp = edge;
    const int* dstp = edge + NE;

    k_count<<<(NE + 255) / 256, 256, 0, stream>>>(dstp, counts);
    k_scan<<<1, 1024, 0, stream>>>(counts, row_ptr, cursor);
    k_scatter<<<(NE + 255) / 256, 256, 0, stream>>>(srcp, dstp, cursor, csr_src);
    k_embed<<<(NN + 3) / 4, 256, 0, stream>>>(x_tokens, emb_table, x0);
    k_convw<<<(HID * EMB) / 256, 256, 0, stream>>>(w1l, w1r, w2l, w2r, wbf);
    k_aggr<<<(NN + 3) / 4, 256, 0, stream>>>(x0, row_ptr, csr_src, aggr);
    k_sage<<<(NN + 127) / 128, 256, 0, stream>>>(aggr, x0, wbf, wbf + 16384, b1, x1);
    k_aggr<<<(NN + 3) / 4, 256, 0, stream>>>(x1, row_ptr, csr_src, aggr);
    k_sage<<<(NN + 127) / 128, 256, 0, stream>>>(aggr, x1, wbf + 32768, wbf + 49152, b2, x2);
    k_pool<<<(NN + 127) / 128, 128, 0, stream>>>(x2, batch, gsum, gcnt);
    k_final<<<NG, 128, 0, stream>>>(gsum, gcnt, w_out, b_out, out);
}

// Round 2
// 393.319 us; speedup vs baseline: 1.2516x; 1.2516x over previous
//
#include <hip/hip_runtime.h>
#include <hip/hip_bf16.h>

#define NN 50000
#define NE 600000
#define BAG 16
#define EMB 128
#define HID 128
#define NC 10
#define NG 512
#define PAD_IDX 1
#define VOCAB 10000
#define NBLK ((NN + 255) / 256)  // 196 scan blocks

typedef __attribute__((ext_vector_type(8))) short v8s;
typedef __attribute__((ext_vector_type(4))) float v4f;

__device__ __forceinline__ float bflo(unsigned u) { return __uint_as_float(u << 16); }
__device__ __forceinline__ float bfhi(unsigned u) { return __uint_as_float(u & 0xffff0000u); }
__device__ __forceinline__ unsigned short f2bf(float f) {
    unsigned u = __float_as_uint(f);
    return (unsigned short)((u + 0x7fffu + ((u >> 16) & 1u)) >> 16);
}

// ---------- CSR build ----------
__global__ void k_count(const int* __restrict__ dst, int* __restrict__ counts) {
    int e = blockIdx.x * blockDim.x + threadIdx.x;
    if (e < NE) atomicAdd(&counts[dst[e]], 1);
}

// phase 1: per-block (256 nodes) sums
__global__ __launch_bounds__(256) void k_bsum(const int* __restrict__ counts,
                                              int* __restrict__ bsum) {
    int blk = blockIdx.x;
    int i = blk * 256 + threadIdx.x;
    int v = (i < NN) ? counts[i] : 0;
#pragma unroll
    for (int off = 32; off; off >>= 1) v += __shfl_down(v, off, 64);
    __shared__ int ws4[4];
    if ((threadIdx.x & 63) == 0) ws4[threadIdx.x >> 6] = v;
    __syncthreads();
    if (threadIdx.x == 0) bsum[blk] = ws4[0] + ws4[1] + ws4[2] + ws4[3];
}

// phase 2: exclusive scan of the 196 block sums (1 tiny block)
__global__ __launch_bounds__(256) void k_bscan(const int* __restrict__ bsum,
                                               int* __restrict__ boff) {
    __shared__ int buf[256];
    int tid = threadIdx.x;
    int v = (tid < NBLK) ? bsum[tid] : 0;
    buf[tid] = v;
    __syncthreads();
    for (int off = 1; off < 256; off <<= 1) {
        int t = (tid >= off) ? buf[tid - off] : 0;
        __syncthreads();
        buf[tid] += t;
        __syncthreads();
    }
    if (tid < NBLK) boff[tid] = buf[tid] - v;  // exclusive
}

// phase 3: intra-block exclusive scan + block offset -> row_ptr, cursor
__global__ __launch_bounds__(256) void k_scan2(const int* __restrict__ counts,
                                               const int* __restrict__ boff,
                                               int* __restrict__ row_ptr,
                                               int* __restrict__ cursor) {
    __shared__ int buf[256];
    int blk = blockIdx.x, tid = threadIdx.x;
    int i = blk * 256 + tid;
    int v = (i < NN) ? counts[i] : 0;
    buf[tid] = v;
    __syncthreads();
    for (int off = 1; off < 256; off <<= 1) {
        int t = (tid >= off) ? buf[tid - off] : 0;
        __syncthreads();
        buf[tid] += t;
        __syncthreads();
    }
    if (i < NN) {
        int ex = boff[blk] + buf[tid] - v;
        row_ptr[i] = ex;
        cursor[i] = ex;
    }
    if (i == 0) row_ptr[NN] = NE;  // all dst in [0,NN) -> total is the edge count
}

__global__ void k_scatter(const int* __restrict__ src, const int* __restrict__ dst,
                          int* __restrict__ cursor, int* __restrict__ csr_src) {
    int e = blockIdx.x * blockDim.x + threadIdx.x;
    if (e < NE) {
        int p = atomicAdd(&cursor[dst[e]], 1);
        csr_src[p] = src[e];
    }
}

// ---------- fp32 -> bf16 embedding table (halves gather traffic in k_embed) ----------
__global__ void k_convt(const float* __restrict__ t, unsigned short* __restrict__ tb) {
    int i = blockIdx.x * blockDim.x + threadIdx.x;  // pair index, 0..640k
    float2 v = *(const float2*)(t + (size_t)i * 2);
    unsigned lo = f2bf(v.x), hi = f2bf(v.y);
    *(unsigned*)(tb + (size_t)i * 2) = lo | (hi << 16);
}

// ---------- embedding bag (mean, excluding PAD_IDX) -> bf16 x0 ----------
__global__ __launch_bounds__(256) void k_embed(const int* __restrict__ tokens,
                                               const unsigned short* __restrict__ table,
                                               unsigned short* __restrict__ x0) {
    int node = blockIdx.x * 4 + (threadIdx.x >> 6);
    int lane = threadIdx.x & 63;
    if (node >= NN) return;
    const int* tp = tokens + node * BAG;
    float ax = 0.f, ay = 0.f;
    int cnt = 0;
#pragma unroll
    for (int t = 0; t < BAG; t++) {
        int tok = tp[t];  // wave-uniform broadcast load
        if (tok != PAD_IDX) {
            unsigned v = *(const unsigned*)(table + (size_t)tok * EMB + lane * 2);
            ax += bflo(v);
            ay += bfhi(v);
            cnt++;
        }
    }
    float inv = 1.0f / (float)(cnt > 0 ? cnt : 1);
    unsigned lo = f2bf(ax * inv), hi = f2bf(ay * inv);
    *(unsigned*)(x0 + (size_t)node * EMB + lane * 2) = lo | (hi << 16);
}

// ---------- fp32 -> bf16 weight conversion ----------
__global__ void k_convw(const float* __restrict__ w1l, const float* __restrict__ w1r,
                        const float* __restrict__ w2l, const float* __restrict__ w2r,
                        unsigned short* __restrict__ wbf) {
    int i = blockIdx.x * blockDim.x + threadIdx.x;  // 0..16383
    wbf[i] = f2bf(w1l[i]);
    wbf[16384 + i] = f2bf(w1r[i]);
    wbf[32768 + i] = f2bf(w2l[i]);
    wbf[49152 + i] = f2bf(w2r[i]);
}

// ---------- neighbor mean aggregation (CSR gather), bf16 in/out, fp32 acc ----------
__global__ __launch_bounds__(256) void k_aggr(const unsigned short* __restrict__ x,
                                              const int* __restrict__ row_ptr,
                                              const int* __restrict__ csr_src,
                                              unsigned short* __restrict__ aggr) {
    int node = blockIdx.x * 4 + (threadIdx.x >> 6);
    int lane = threadIdx.x & 63;
    if (node >= NN) return;
    int s = row_ptr[node], e = row_ptr[node + 1];
    float ax = 0.f, ay = 0.f;
    for (int i = s; i < e; i++) {
        int src = csr_src[i];  // wave-uniform broadcast load
        unsigned v = *(const unsigned*)(x + (size_t)src * HID + lane * 2);
        ax += bflo(v);
        ay += bfhi(v);
    }
    int deg = e - s;
    float inv = 1.0f / (float)(deg > 0 ? deg : 1);
    unsigned lo = f2bf(ax * inv), hi = f2bf(ay * inv);
    *(unsigned*)(aggr + (size_t)node * HID + lane * 2) = lo | (hi << 16);
}

// ---------- fused SAGE linear: relu(aggr@wl^T + b + x@wr^T), MFMA bf16 ----------
__global__ __launch_bounds__(256) void k_sage(const unsigned short* __restrict__ xa,
                                              const unsigned short* __restrict__ xr,
                                              const unsigned short* __restrict__ wl,
                                              const unsigned short* __restrict__ wr,
                                              const float* __restrict__ bias,
                                              unsigned short* __restrict__ out) {
    __shared__ unsigned short As[128 * 32];
    __shared__ unsigned short Bs[128 * 32];
    int tid = threadIdx.x;
    int wave = tid >> 6, lane = tid & 63;
    int q = lane >> 4, l16 = lane & 15;
    int row0 = blockIdx.x * 128;

    v4f acc[2][8];
#pragma unroll
    for (int m = 0; m < 2; m++)
#pragma unroll
        for (int n = 0; n < 8; n++) acc[m][n] = (v4f){0.f, 0.f, 0.f, 0.f};

    for (int kc = 0; kc < 8; kc++) {
        const unsigned short* Ag = (kc < 4) ? xa : xr;
        const unsigned short* Bg = (kc < 4) ? wl : wr;
        int koff = (kc & 3) * 32;
#pragma unroll
        for (int it = 0; it < 2; it++) {
            int seg = tid + it * 256;  // 0..511 : 128 rows x 4 segments of 8 bf16
            int r = seg >> 2, sg = seg & 3;
            int gr = row0 + r;
            if (gr > NN - 1) gr = NN - 1;
            v8s a = *(const v8s*)(Ag + (size_t)gr * HID + koff + sg * 8);
            *(v8s*)(As + r * 32 + sg * 8) = a;
            v8s b = *(const v8s*)(Bg + (size_t)r * HID + koff + sg * 8);
            *(v8s*)(Bs + r * 32 + sg * 8) = b;
        }
        __syncthreads();
        v8s a0 = *(const v8s*)(As + (wave * 32 + l16) * 32 + q * 8);
        v8s a1 = *(const v8s*)(As + (wave * 32 + 16 + l16) * 32 + q * 8);
#pragma unroll
        for (int nt = 0; nt < 8; nt++) {
            v8s b = *(const v8s*)(Bs + (nt * 16 + l16) * 32 + q * 8);
            acc[0][nt] = __builtin_amdgcn_mfma_f32_16x16x32_bf16(a0, b, acc[0][nt], 0, 0, 0);
            acc[1][nt] = __builtin_amdgcn_mfma_f32_16x16x32_bf16(a1, b, acc[1][nt], 0, 0, 0);
        }
        __syncthreads();
    }
    // epilogue: C/D layout col=lane&15, row=quad*4+reg (m89-verified)
#pragma unroll
    for (int nt = 0; nt < 8; nt++) {
        int col = nt * 16 + l16;
        float bv = bias[col];
#pragma unroll
        for (int mt = 0; mt < 2; mt++) {
#pragma unroll
            for (int r = 0; r < 4; r++) {
                int row = row0 + wave * 32 + mt * 16 + q * 4 + r;
                if (row < NN) {
                    float v = acc[mt][nt][r] + bv;
                    v = v > 0.f ? v : 0.f;
                    out[(size_t)row * HID + col] = f2bf(v);
                }
            }
        }
    }
}

// ---------- global mean pool (batch sorted): run-length local acc, few atomics ----------
__global__ __launch_bounds__(128) void k_pool(const unsigned short* __restrict__ x2,
                                              const int* __restrict__ batch,
                                              float* __restrict__ gsum,
                                              float* __restrict__ gcnt) {
    int tid = threadIdx.x;
    int start = blockIdx.x * 128;
    int end = start + 128;
    if (end > NN) end = NN;
    int cur = batch[start];
    float acc = 0.f;
    int cnt = 0;
    for (int n = start; n < end; n++) {
        int b = batch[n];  // uniform across block
        if (b != cur) {
            atomicAdd(&gsum[cur * HID + tid], acc);
            if (tid == 0) atomicAdd(&gcnt[cur], (float)cnt);
            acc = 0.f;
            cnt = 0;
            cur = b;
        }
        acc += __uint_as_float(((unsigned)x2[(size_t)n * HID + tid]) << 16);
        cnt++;
    }
    atomicAdd(&gsum[cur * HID + tid], acc);
    if (tid == 0) atomicAdd(&gcnt[cur], (float)cnt);
}

// ---------- final classifier: out = (gsum/gcnt) @ w_out^T + b_out ----------
__global__ __launch_bounds__(128) void k_final(const float* __restrict__ gsum,
                                               const float* __restrict__ gcnt,
                                               const float* __restrict__ w_out,
                                               const float* __restrict__ b_out,
                                               float* __restrict__ out) {
    __shared__ float mean[HID];
    int g = blockIdx.x, tid = threadIdx.x;
    float c = gcnt[g];
    float ic = 1.0f / fmaxf(c, 1.0f);
    mean[tid] = gsum[g * HID + tid] * ic;
    __syncthreads();
    if (tid < NC) {
        float s = b_out[tid];
#pragma unroll 16
        for (int d = 0; d < HID; d++) s += mean[d] * w_out[tid * HID + d];
        out[g * NC + tid] = s;
    }
}

extern "C" void kernel_launch(void* const* d_in, const int* in_sizes, int n_in,
                              void* d_out, int out_size, void* d_ws, size_t ws_size,
                              hipStream_t stream) {
    const int* x_tokens = (const int*)d_in[0];
    const int* edge = (const int*)d_in[1];
    const int* batch = (const int*)d_in[2];
    const float* emb_table = (const float*)d_in[3];
    const float* w1l = (const float*)d_in[4];
    const float* b1 = (const float*)d_in[5];
    const float* w1r = (const float*)d_in[6];
    const float* w2l = (const float*)d_in[7];
    const float* b2 = (const float*)d_in[8];
    const float* w2r = (const float*)d_in[9];
    const float* w_out = (const float*)d_in[10];
    const float* b_out = (const float*)d_in[11];
    float* out = (float*)d_out;

    char* ws = (char*)d_ws;
    size_t off = 0;
    auto alloc = [&](size_t bytes) {
        void* p = ws + off;
        off += (bytes + 255) & ~(size_t)255;
        return p;
    };
    int* counts = (int*)alloc(NN * 4);
    int* row_ptr = (int*)alloc((NN + 1) * 4);
    int* cursor = (int*)alloc(NN * 4);
    int* csr_src = (int*)alloc(NE * 4);
    int* bsum = (int*)alloc(NBLK * 4);
    int* boff = (int*)alloc(NBLK * 4);
    unsigned short* wbf = (unsigned short*)alloc(4 * HID * EMB * 2);
    float* gsum = (float*)alloc(NG * HID * 4);
    float* gcnt = (float*)alloc(NG * 4);
    unsigned short* x0 = (unsigned short*)alloc((size_t)NN * EMB * 2);
    unsigned short* x1 = (unsigned short*)alloc((size_t)NN * HID * 2);
    unsigned short* aggr = (unsigned short*)alloc((size_t)NN * HID * 2);
    unsigned short* x2 = x0;           // x0 dead after layer-1 GEMM; reuse
    unsigned short* table_bf = x1;     // x1 dead until layer-1 GEMM writes it; reuse

    hipMemsetAsync(counts, 0, NN * 4, stream);
    hipMemsetAsync(gsum, 0, NG * HID * 4, stream);
    hipMemsetAsync(gcnt, 0, NG * 4, stream);

    const int* srcp = edge;
    const int* dstp = edge + NE;

    k_count<<<(NE + 255) / 256, 256, 0, stream>>>(dstp, counts);
    k_bsum<<<NBLK, 256, 0, stream>>>(counts, bsum);
    k_bscan<<<1, 256, 0, stream>>>(bsum, boff);
    k_scan2<<<NBLK, 256, 0, stream>>>(counts, boff, row_ptr, cursor);
    k_scatter<<<(NE + 255) / 256, 256, 0, stream>>>(srcp, dstp, cursor, csr_src);
    k_convt<<<(VOCAB * EMB / 2) / 256, 256, 0, stream>>>(emb_table, table_bf);
    k_embed<<<(NN + 3) / 4, 256, 0, stream>>>(x_tokens, table_bf, x0);
    k_convw<<<(HID * EMB) / 256, 256, 0, stream>>>(w1l, w1r, w2l, w2r, wbf);
    k_aggr<<<(NN + 3) / 4, 256, 0, stream>>>(x0, row_ptr, csr_src, aggr);
    k_sage<<<(NN + 127) / 128, 256, 0, stream>>>(aggr, x0, wbf, wbf + 16384, b1, x1);
    k_aggr<<<(NN + 3) / 4, 256, 0, stream>>>(x1, row_ptr, csr_src, aggr);
    k_sage<<<(NN + 127) / 128, 256, 0, stream>>>(aggr, x1, wbf + 32768, wbf + 49152, b2, x2);
    k_pool<<<(NN + 127) / 128, 128, 0, stream>>>(x2, batch, gsum, gcnt);
    k_final<<<NG, 128, 0, stream>>>(gsum, gcnt, w_out, b_out, out);
}

// Round 3
// 323.546 us; speedup vs baseline: 1.5215x; 1.2157x over previous
//
#include <hip/hip_runtime.h>
#include <hip/hip_bf16.h>

#define NN 50000
#define NE 600000
#define BAG 16
#define EMB 128
#define HID 128
#define NC 10
#define NG 512
#define PAD_IDX 1
#define VOCAB 10000
#define NBLK ((NN + 255) / 256)  // 196 scan blocks
#define TPAIRS (VOCAB * EMB / 2) // 640k bf16 pairs in the table

typedef __attribute__((ext_vector_type(8))) short v8s;
typedef __attribute__((ext_vector_type(4))) float v4f;

__device__ __forceinline__ float bflo(unsigned u) { return __uint_as_float(u << 16); }
__device__ __forceinline__ float bfhi(unsigned u) { return __uint_as_float(u & 0xffff0000u); }
__device__ __forceinline__ unsigned short f2bf(float f) {
    unsigned u = __float_as_uint(f);
    return (unsigned short)((u + 0x7fffu + ((u >> 16) & 1u)) >> 16);
}

// ---------- CSR build ----------
__global__ void k_count(const int* __restrict__ dst, int* __restrict__ counts) {
    int e = blockIdx.x * blockDim.x + threadIdx.x;
    if (e < NE) atomicAdd(&counts[dst[e]], 1);
}

// phase 1: per-block (256 nodes) sums
__global__ __launch_bounds__(256) void k_bsum(const int* __restrict__ counts,
                                              int* __restrict__ bsum) {
    int blk = blockIdx.x;
    int i = blk * 256 + threadIdx.x;
    int v = (i < NN) ? counts[i] : 0;
#pragma unroll
    for (int off = 32; off; off >>= 1) v += __shfl_down(v, off, 64);
    __shared__ int ws4[4];
    if ((threadIdx.x & 63) == 0) ws4[threadIdx.x >> 6] = v;
    __syncthreads();
    if (threadIdx.x == 0) bsum[blk] = ws4[0] + ws4[1] + ws4[2] + ws4[3];
}

// phase 2+3 fused: block offset = reduce(bsum[0..blk)), then intra-block scan
__global__ __launch_bounds__(256) void k_scan2(const int* __restrict__ counts,
                                               const int* __restrict__ bsum,
                                               int* __restrict__ row_ptr,
                                               int* __restrict__ cursor) {
    __shared__ int buf[256];
    __shared__ int off_s;
    int blk = blockIdx.x, tid = threadIdx.x;
    // block offset: sum of bsum[t] for t < blk
    int bv = (tid < blk) ? bsum[tid] : 0;  // NBLK=196 <= 256
#pragma unroll
    for (int off = 32; off; off >>= 1) bv += __shfl_down(bv, off, 64);
    __shared__ int ws4[4];
    if ((tid & 63) == 0) ws4[tid >> 6] = bv;
    __syncthreads();
    if (tid == 0) off_s = ws4[0] + ws4[1] + ws4[2] + ws4[3];
    // intra-block inclusive scan of counts
    int i = blk * 256 + tid;
    int v = (i < NN) ? counts[i] : 0;
    buf[tid] = v;
    __syncthreads();
    for (int off = 1; off < 256; off <<= 1) {
        int t = (tid >= off) ? buf[tid - off] : 0;
        __syncthreads();
        buf[tid] += t;
        __syncthreads();
    }
    if (i < NN) {
        int ex = off_s + buf[tid] - v;
        row_ptr[i] = ex;
        cursor[i] = ex;
    }
    if (i == 0) row_ptr[NN] = NE;  // all dst in [0,NN) -> total is the edge count
}

__global__ void k_scatter(const int* __restrict__ src, const int* __restrict__ dst,
                          int* __restrict__ cursor, int* __restrict__ csr_src) {
    int e = blockIdx.x * blockDim.x + threadIdx.x;
    if (e < NE) {
        int p = atomicAdd(&cursor[dst[e]], 1);
        csr_src[p] = src[e];
    }
}

// ---------- fp32 -> bf16 conversion: embedding table + all 4 weight matrices ----------
__global__ void k_conv(const float* __restrict__ t, unsigned short* __restrict__ tb,
                       const float* __restrict__ w1l, const float* __restrict__ w1r,
                       const float* __restrict__ w2l, const float* __restrict__ w2r,
                       unsigned short* __restrict__ wbf) {
    int i = blockIdx.x * blockDim.x + threadIdx.x;  // pair index
    if (i < TPAIRS) {
        float2 v = *(const float2*)(t + (size_t)i * 2);
        unsigned lo = f2bf(v.x), hi = f2bf(v.y);
        *(unsigned*)(tb + (size_t)i * 2) = lo | (hi << 16);
    } else {
        int j = i - TPAIRS;  // 0..32767 weight pairs
        if (j >= 4 * HID * EMB / 2) return;
        int k = j * 2;               // element index in concatenated [w1l|w1r|w2l|w2r]
        int arr = k >> 14;           // 16384 elements per matrix
        int o = k & 16383;
        const float* w = (arr == 0) ? w1l : (arr == 1) ? w1r : (arr == 2) ? w2l : w2r;
        float2 v = *(const float2*)(w + o);
        unsigned lo = f2bf(v.x), hi = f2bf(v.y);
        *(unsigned*)(wbf + k) = lo | (hi << 16);
    }
}

// ---------- embedding bag (mean, excluding PAD_IDX) -> bf16 x0 ----------
__global__ __launch_bounds__(256) void k_embed(const int* __restrict__ tokens,
                                               const unsigned short* __restrict__ table,
                                               unsigned short* __restrict__ x0) {
    int node = blockIdx.x * 4 + (threadIdx.x >> 6);
    int lane = threadIdx.x & 63;
    if (node >= NN) return;
    const int* tp = tokens + node * BAG;
    float ax = 0.f, ay = 0.f;
    int cnt = 0;
#pragma unroll
    for (int t = 0; t < BAG; t++) {
        int tok = tp[t];  // wave-uniform broadcast load
        if (tok != PAD_IDX) {
            unsigned v = *(const unsigned*)(table + (size_t)tok * EMB + lane * 2);
            ax += bflo(v);
            ay += bfhi(v);
            cnt++;
        }
    }
    float inv = 1.0f / (float)(cnt > 0 ? cnt : 1);
    unsigned lo = f2bf(ax * inv), hi = f2bf(ay * inv);
    *(unsigned*)(x0 + (size_t)node * EMB + lane * 2) = lo | (hi << 16);
}

// ---------- neighbor mean aggregation (CSR gather), 8-way MLP unroll ----------
__global__ __launch_bounds__(256) void k_aggr(const unsigned short* __restrict__ x,
                                              const int* __restrict__ row_ptr,
                                              const int* __restrict__ csr_src,
                                              unsigned short* __restrict__ aggr) {
    int node = blockIdx.x * 4 + (threadIdx.x >> 6);
    int lane = threadIdx.x & 63;
    if (node >= NN) return;
    int s = row_ptr[node], e = row_ptr[node + 1];
    float ax = 0.f, ay = 0.f;
    int i = s;
    // 8-deep batch: independent index loads, then 8 independent row gathers in flight
    for (; i + 8 <= e; i += 8) {
        int idx[8];
#pragma unroll
        for (int j = 0; j < 8; j++) idx[j] = csr_src[i + j];
        unsigned v[8];
#pragma unroll
        for (int j = 0; j < 8; j++)
            v[j] = *(const unsigned*)(x + (size_t)idx[j] * HID + lane * 2);
#pragma unroll
        for (int j = 0; j < 8; j++) {
            ax += bflo(v[j]);
            ay += bfhi(v[j]);
        }
    }
    for (; i + 2 <= e; i += 2) {
        int i0 = csr_src[i], i1 = csr_src[i + 1];
        unsigned v0 = *(const unsigned*)(x + (size_t)i0 * HID + lane * 2);
        unsigned v1 = *(const unsigned*)(x + (size_t)i1 * HID + lane * 2);
        ax += bflo(v0) + bflo(v1);
        ay += bfhi(v0) + bfhi(v1);
    }
    for (; i < e; i++) {
        int i0 = csr_src[i];
        unsigned v0 = *(const unsigned*)(x + (size_t)i0 * HID + lane * 2);
        ax += bflo(v0);
        ay += bfhi(v0);
    }
    int deg = e - s;
    float inv = 1.0f / (float)(deg > 0 ? deg : 1);
    unsigned lo = f2bf(ax * inv), hi = f2bf(ay * inv);
    *(unsigned*)(aggr + (size_t)node * HID + lane * 2) = lo | (hi << 16);
}

// ---------- fused SAGE linear: relu(aggr@wl^T + b + x@wr^T), MFMA bf16 ----------
__global__ __launch_bounds__(256) void k_sage(const unsigned short* __restrict__ xa,
                                              const unsigned short* __restrict__ xr,
                                              const unsigned short* __restrict__ wl,
                                              const unsigned short* __restrict__ wr,
                                              const float* __restrict__ bias,
                                              unsigned short* __restrict__ out) {
    __shared__ unsigned short As[128 * 32];
    __shared__ unsigned short Bs[128 * 32];
    int tid = threadIdx.x;
    int wave = tid >> 6, lane = tid & 63;
    int q = lane >> 4, l16 = lane & 15;
    int row0 = blockIdx.x * 128;

    v4f acc[2][8];
#pragma unroll
    for (int m = 0; m < 2; m++)
#pragma unroll
        for (int n = 0; n < 8; n++) acc[m][n] = (v4f){0.f, 0.f, 0.f, 0.f};

    for (int kc = 0; kc < 8; kc++) {
        const unsigned short* Ag = (kc < 4) ? xa : xr;
        const unsigned short* Bg = (kc < 4) ? wl : wr;
        int koff = (kc & 3) * 32;
#pragma unroll
        for (int it = 0; it < 2; it++) {
            int seg = tid + it * 256;  // 0..511 : 128 rows x 4 segments of 8 bf16
            int r = seg >> 2, sg = seg & 3;
            int gr = row0 + r;
            if (gr > NN - 1) gr = NN - 1;
            v8s a = *(const v8s*)(Ag + (size_t)gr * HID + koff + sg * 8);
            *(v8s*)(As + r * 32 + sg * 8) = a;
            v8s b = *(const v8s*)(Bg + (size_t)r * HID + koff + sg * 8);
            *(v8s*)(Bs + r * 32 + sg * 8) = b;
        }
        __syncthreads();
        v8s a0 = *(const v8s*)(As + (wave * 32 + l16) * 32 + q * 8);
        v8s a1 = *(const v8s*)(As + (wave * 32 + 16 + l16) * 32 + q * 8);
#pragma unroll
        for (int nt = 0; nt < 8; nt++) {
            v8s b = *(const v8s*)(Bs + (nt * 16 + l16) * 32 + q * 8);
            acc[0][nt] = __builtin_amdgcn_mfma_f32_16x16x32_bf16(a0, b, acc[0][nt], 0, 0, 0);
            acc[1][nt] = __builtin_amdgcn_mfma_f32_16x16x32_bf16(a1, b, acc[1][nt], 0, 0, 0);
        }
        __syncthreads();
    }
    // epilogue: C/D layout col=lane&15, row=quad*4+reg (m89-verified)
#pragma unroll
    for (int nt = 0; nt < 8; nt++) {
        int col = nt * 16 + l16;
        float bv = bias[col];
#pragma unroll
        for (int mt = 0; mt < 2; mt++) {
#pragma unroll
            for (int r = 0; r < 4; r++) {
                int row = row0 + wave * 32 + mt * 16 + q * 4 + r;
                if (row < NN) {
                    float v = acc[mt][nt][r] + bv;
                    v = v > 0.f ? v : 0.f;
                    out[(size_t)row * HID + col] = f2bf(v);
                }
            }
        }
    }
}

// ---------- global mean pool (batch sorted): run-length local acc, few atomics ----------
__global__ __launch_bounds__(128) void k_pool(const unsigned short* __restrict__ x2,
                                              const int* __restrict__ batch,
                                              float* __restrict__ gsum,
                                              float* __restrict__ gcnt) {
    int tid = threadIdx.x;
    int start = blockIdx.x * 128;
    int end = start + 128;
    if (end > NN) end = NN;
    int cur = batch[start];
    float acc = 0.f;
    int cnt = 0;
    for (int n = start; n < end; n++) {
        int b = batch[n];  // uniform across block
        if (b != cur) {
            atomicAdd(&gsum[cur * HID + tid], acc);
            if (tid == 0) atomicAdd(&gcnt[cur], (float)cnt);
            acc = 0.f;
            cnt = 0;
            cur = b;
        }
        acc += __uint_as_float(((unsigned)x2[(size_t)n * HID + tid]) << 16);
        cnt++;
    }
    atomicAdd(&gsum[cur * HID + tid], acc);
    if (tid == 0) atomicAdd(&gcnt[cur], (float)cnt);
}

// ---------- final classifier: out = (gsum/gcnt) @ w_out^T + b_out ----------
__global__ __launch_bounds__(128) void k_final(const float* __restrict__ gsum,
                                               const float* __restrict__ gcnt,
                                               const float* __restrict__ w_out,
                                               const float* __restrict__ b_out,
                                               float* __restrict__ out) {
    __shared__ float mean[HID];
    int g = blockIdx.x, tid = threadIdx.x;
    float c = gcnt[g];
    float ic = 1.0f / fmaxf(c, 1.0f);
    mean[tid] = gsum[g * HID + tid] * ic;
    __syncthreads();
    if (tid < NC) {
        float s = b_out[tid];
#pragma unroll 16
        for (int d = 0; d < HID; d++) s += mean[d] * w_out[tid * HID + d];
        out[g * NC + tid] = s;
    }
}

extern "C" void kernel_launch(void* const* d_in, const int* in_sizes, int n_in,
                              void* d_out, int out_size, void* d_ws, size_t ws_size,
                              hipStream_t stream) {
    const int* x_tokens = (const int*)d_in[0];
    const int* edge = (const int*)d_in[1];
    const int* batch = (const int*)d_in[2];
    const float* emb_table = (const float*)d_in[3];
    const float* w1l = (const float*)d_in[4];
    const float* b1 = (const float*)d_in[5];
    const float* w1r = (const float*)d_in[6];
    const float* w2l = (const float*)d_in[7];
    const float* b2 = (const float*)d_in[8];
    const float* w2r = (const float*)d_in[9];
    const float* w_out = (const float*)d_in[10];
    const float* b_out = (const float*)d_in[11];
    float* out = (float*)d_out;

    char* ws = (char*)d_ws;
    size_t off = 0;
    auto alloc = [&](size_t bytes) {
        void* p = ws + off;
        off += (bytes + 255) & ~(size_t)255;
        return p;
    };
    int* counts = (int*)alloc(NN * 4);
    int* row_ptr = (int*)alloc((NN + 1) * 4);
    int* cursor = (int*)alloc(NN * 4);
    int* csr_src = (int*)alloc(NE * 4);
    int* bsum = (int*)alloc(NBLK * 4);
    unsigned short* wbf = (unsigned short*)alloc(4 * HID * EMB * 2);
    float* gsum = (float*)alloc(NG * HID * 4);
    float* gcnt = (float*)alloc(NG * 4);
    unsigned short* x0 = (unsigned short*)alloc((size_t)NN * EMB * 2);
    unsigned short* x1 = (unsigned short*)alloc((size_t)NN * HID * 2);
    unsigned short* aggr = (unsigned short*)alloc((size_t)NN * HID * 2);
    unsigned short* x2 = x0;           // x0 dead after layer-1 GEMM; reuse
    unsigned short* table_bf = x1;     // x1 dead until layer-1 GEMM writes it; reuse

    hipMemsetAsync(counts, 0, NN * 4, stream);
    hipMemsetAsync(gsum, 0, NG * HID * 4, stream);
    hipMemsetAsync(gcnt, 0, NG * 4, stream);

    const int* srcp = edge;
    const int* dstp = edge + NE;

    k_count<<<(NE + 255) / 256, 256, 0, stream>>>(dstp, counts);
    k_bsum<<<NBLK, 256, 0, stream>>>(counts, bsum);
    k_scan2<<<NBLK, 256, 0, stream>>>(counts, bsum, row_ptr, cursor);
    k_scatter<<<(NE + 255) / 256, 256, 0, stream>>>(srcp, dstp, cursor, csr_src);
    k_conv<<<(TPAIRS + 4 * HID * EMB / 2 + 255) / 256, 256, 0, stream>>>(
        emb_table, table_bf, w1l, w1r, w2l, w2r, wbf);
    k_embed<<<(NN + 3) / 4, 256, 0, stream>>>(x_tokens, table_bf, x0);
    k_aggr<<<(NN + 3) / 4, 256, 0, stream>>>(x0, row_ptr, csr_src, aggr);
    k_sage<<<(NN + 127) / 128, 256, 0, stream>>>(aggr, x0, wbf, wbf + 16384, b1, x1);
    k_aggr<<<(NN + 3) / 4, 256, 0, stream>>>(x1, row_ptr, csr_src, aggr);
    k_sage<<<(NN + 127) / 128, 256, 0, stream>>>(aggr, x1, wbf + 32768, wbf + 49152, b2, x2);
    k_pool<<<(NN + 127) / 128, 128, 0, stream>>>(x2, batch, gsum, gcnt);
    k_final<<<NG, 128, 0, stream>>>(gsum, gcnt, w_out, b_out, out);
}

// Round 4
// 289.762 us; speedup vs baseline: 1.6989x; 1.1166x over previous
//
#include <hip/hip_runtime.h>
#include <hip/hip_bf16.h>

#define NN 50000
#define NE 600000
#define BAG 16
#define EMB 128
#define HID 128
#define NC 10
#define NG 512
#define PAD_IDX 1
#define VOCAB 10000
#define NBLK ((NN + 255) / 256)  // 196 scan blocks
#define TPAIRS (VOCAB * EMB / 2) // 640k bf16 pairs in the table
#define WPAIRS (4 * HID * EMB / 2)

typedef __attribute__((ext_vector_type(8))) short v8s;
typedef __attribute__((ext_vector_type(4))) float v4f;

__device__ __forceinline__ float bflo(unsigned u) { return __uint_as_float(u << 16); }
__device__ __forceinline__ float bfhi(unsigned u) { return __uint_as_float(u & 0xffff0000u); }
__device__ __forceinline__ unsigned short f2bf(float f) {
    unsigned u = __float_as_uint(f);
    return (unsigned short)((u + 0x7fffu + ((u >> 16) & 1u)) >> 16);
}
__device__ __forceinline__ void acc8(float* a, v8s v) {
    unsigned* u = (unsigned*)&v;
#pragma unroll
    for (int j = 0; j < 4; j++) {
        a[2 * j] += bflo(u[j]);
        a[2 * j + 1] += bfhi(u[j]);
    }
}

// ---------- CSR build ----------
__global__ void k_count(const int* __restrict__ dst, int* __restrict__ counts) {
    int e = blockIdx.x * blockDim.x + threadIdx.x;
    if (e < NE) atomicAdd(&counts[dst[e]], 1);
}

__global__ __launch_bounds__(256) void k_bsum(const int* __restrict__ counts,
                                              int* __restrict__ bsum) {
    int blk = blockIdx.x;
    int i = blk * 256 + threadIdx.x;
    int v = (i < NN) ? counts[i] : 0;
#pragma unroll
    for (int off = 32; off; off >>= 1) v += __shfl_down(v, off, 64);
    __shared__ int ws4[4];
    if ((threadIdx.x & 63) == 0) ws4[threadIdx.x >> 6] = v;
    __syncthreads();
    if (threadIdx.x == 0) bsum[blk] = ws4[0] + ws4[1] + ws4[2] + ws4[3];
}

// block offset = reduce(bsum[0..blk)), then intra-block scan
__global__ __launch_bounds__(256) void k_scan2(const int* __restrict__ counts,
                                               const int* __restrict__ bsum,
                                               int* __restrict__ row_ptr,
                                               int* __restrict__ cursor) {
    __shared__ int buf[256];
    __shared__ int off_s;
    int blk = blockIdx.x, tid = threadIdx.x;
    int bv = (tid < blk) ? bsum[tid] : 0;  // NBLK=196 <= 256
#pragma unroll
    for (int off = 32; off; off >>= 1) bv += __shfl_down(bv, off, 64);
    __shared__ int ws4[4];
    if ((tid & 63) == 0) ws4[tid >> 6] = bv;
    __syncthreads();
    if (tid == 0) off_s = ws4[0] + ws4[1] + ws4[2] + ws4[3];
    int i = blk * 256 + tid;
    int v = (i < NN) ? counts[i] : 0;
    buf[tid] = v;
    __syncthreads();
    for (int off = 1; off < 256; off <<= 1) {
        int t = (tid >= off) ? buf[tid - off] : 0;
        __syncthreads();
        buf[tid] += t;
        __syncthreads();
    }
    if (i < NN) {
        int ex = off_s + buf[tid] - v;
        row_ptr[i] = ex;
        cursor[i] = ex;
    }
    if (i == 0) row_ptr[NN] = NE;
}

__global__ void k_scatter(const int* __restrict__ src, const int* __restrict__ dst,
                          int* __restrict__ cursor, int* __restrict__ csr_src) {
    int e = blockIdx.x * blockDim.x + threadIdx.x;
    if (e < NE) {
        int p = atomicAdd(&cursor[dst[e]], 1);
        csr_src[p] = src[e];
    }
}

// ---------- fp32->bf16 conversion (table + weights) and workspace zeroing ----------
__global__ void k_conv(const float* __restrict__ t, unsigned short* __restrict__ tb,
                       const float* __restrict__ w1l, const float* __restrict__ w1r,
                       const float* __restrict__ w2l, const float* __restrict__ w2r,
                       unsigned short* __restrict__ wbf, int* __restrict__ counts,
                       float* __restrict__ gsum, float* __restrict__ gcnt) {
    int i = blockIdx.x * blockDim.x + threadIdx.x;  // pair index
    // zeroing (ws is poisoned 0xAA before every call)
    if (i < NN) counts[i] = 0;
    if (i < NG * HID) gsum[i] = 0.f;
    if (i < NG) gcnt[i] = 0.f;
    if (i < TPAIRS) {
        float2 v = *(const float2*)(t + (size_t)i * 2);
        unsigned lo = f2bf(v.x), hi = f2bf(v.y);
        *(unsigned*)(tb + (size_t)i * 2) = lo | (hi << 16);
    } else {
        int j = i - TPAIRS;
        if (j >= WPAIRS) return;
        int k = j * 2;      // element index in concatenated [w1l|w1r|w2l|w2r]
        int arr = k >> 14;  // 16384 elements per matrix
        int o = k & 16383;
        const float* w = (arr == 0) ? w1l : (arr == 1) ? w1r : (arr == 2) ? w2l : w2r;
        float2 v = *(const float2*)(w + o);
        unsigned lo = f2bf(v.x), hi = f2bf(v.y);
        *(unsigned*)(wbf + k) = lo | (hi << 16);
    }
}

// ---------- embedding bag mean -> bf16 x0 ----------
// One wave per node. dwordx4 gathers: 16 lanes cover a 256B row -> 4 rows/load.
// PAD row of the table is exactly zero -> sum unconditionally, mask only the count.
__global__ __launch_bounds__(256) void k_embed(const int* __restrict__ tokens,
                                               const unsigned short* __restrict__ table,
                                               unsigned short* __restrict__ x0) {
    int node = blockIdx.x * 4 + (threadIdx.x >> 6);
    int lane = threadIdx.x & 63;
    if (node >= NN) return;
    const int* tp = tokens + node * BAG;
    int g = lane >> 4;   // which of 4 rows this lane helps gather
    int sl = lane & 15;  // 16B slice within the row
    int tok_l = tp[sl];  // bag token at position (lane&15), replicated 4x
    unsigned long long m = __ballot(tok_l != PAD_IDX);
    int cnt = __popcll(m & 0xFFFFull);
    float a[8];
#pragma unroll
    for (int j = 0; j < 8; j++) a[j] = 0.f;
#pragma unroll
    for (int it = 0; it < 4; it++) {
        int tok = __shfl(tok_l, it * 4 + g, 64);
        v8s v = *(const v8s*)(table + (size_t)tok * EMB + sl * 8);
        acc8(a, v);
    }
#pragma unroll
    for (int j = 0; j < 8; j++) {
        a[j] += __shfl_xor(a[j], 16, 64);
        a[j] += __shfl_xor(a[j], 32, 64);
    }
    float inv = 1.0f / (float)(cnt > 0 ? cnt : 1);
    if (g == 0) {
        uint4 o;
        o.x = f2bf(a[0] * inv) | ((unsigned)f2bf(a[1] * inv) << 16);
        o.y = f2bf(a[2] * inv) | ((unsigned)f2bf(a[3] * inv) << 16);
        o.z = f2bf(a[4] * inv) | ((unsigned)f2bf(a[5] * inv) << 16);
        o.w = f2bf(a[6] * inv) | ((unsigned)f2bf(a[7] * inv) << 16);
        *(uint4*)(x0 + (size_t)node * EMB + sl * 8) = o;
    }
}

// ---------- neighbor mean aggregation: dwordx4 gathers, 4 edges/load ----------
__global__ __launch_bounds__(256) void k_aggr(const unsigned short* __restrict__ x,
                                              const int* __restrict__ row_ptr,
                                              const int* __restrict__ csr_src,
                                              unsigned short* __restrict__ aggr) {
    int node = blockIdx.x * 4 + (threadIdx.x >> 6);
    int lane = threadIdx.x & 63;
    if (node >= NN) return;
    int s = row_ptr[node], e = row_ptr[node + 1];
    int g = lane >> 4, sl = lane & 15;
    float a[8];
#pragma unroll
    for (int j = 0; j < 8; j++) a[j] = 0.f;
    int i = s;
    for (; i + 16 <= e; i += 16) {  // 4 KB in flight
        int i0 = csr_src[i + g];
        int i1 = csr_src[i + 4 + g];
        int i2 = csr_src[i + 8 + g];
        int i3 = csr_src[i + 12 + g];
        v8s v0 = *(const v8s*)(x + (size_t)i0 * HID + sl * 8);
        v8s v1 = *(const v8s*)(x + (size_t)i1 * HID + sl * 8);
        v8s v2 = *(const v8s*)(x + (size_t)i2 * HID + sl * 8);
        v8s v3 = *(const v8s*)(x + (size_t)i3 * HID + sl * 8);
        acc8(a, v0);
        acc8(a, v1);
        acc8(a, v2);
        acc8(a, v3);
    }
    for (; i + 8 <= e; i += 8) {
        int i0 = csr_src[i + g];
        int i1 = csr_src[i + 4 + g];
        v8s v0 = *(const v8s*)(x + (size_t)i0 * HID + sl * 8);
        v8s v1 = *(const v8s*)(x + (size_t)i1 * HID + sl * 8);
        acc8(a, v0);
        acc8(a, v1);
    }
    for (; i + 4 <= e; i += 4) {
        int i0 = csr_src[i + g];
        v8s v0 = *(const v8s*)(x + (size_t)i0 * HID + sl * 8);
        acc8(a, v0);
    }
    int rem = e - i;  // 0..3
    if (rem > 0) {
        int gi = (g < rem) ? g : 0;
        int i0 = csr_src[i + gi];
        v8s v0 = *(const v8s*)(x + (size_t)i0 * HID + sl * 8);
        if (g < rem) acc8(a, v0);  // masked add; duplicate-group loads not accumulated
    }
#pragma unroll
    for (int j = 0; j < 8; j++) {
        a[j] += __shfl_xor(a[j], 16, 64);
        a[j] += __shfl_xor(a[j], 32, 64);
    }
    int deg = e - s;
    float inv = 1.0f / (float)(deg > 0 ? deg : 1);
    if (g == 0) {
        uint4 o;
        o.x = f2bf(a[0] * inv) | ((unsigned)f2bf(a[1] * inv) << 16);
        o.y = f2bf(a[2] * inv) | ((unsigned)f2bf(a[3] * inv) << 16);
        o.z = f2bf(a[4] * inv) | ((unsigned)f2bf(a[5] * inv) << 16);
        o.w = f2bf(a[6] * inv) | ((unsigned)f2bf(a[7] * inv) << 16);
        *(uint4*)(aggr + (size_t)node * HID + sl * 8) = o;
    }
}

// ---------- fused SAGE linear: relu(aggr@wl^T + b + x@wr^T), MFMA bf16 ----------
__global__ __launch_bounds__(256) void k_sage(const unsigned short* __restrict__ xa,
                                              const unsigned short* __restrict__ xr,
                                              const unsigned short* __restrict__ wl,
                                              const unsigned short* __restrict__ wr,
                                              const float* __restrict__ bias,
                                              unsigned short* __restrict__ out) {
    __shared__ unsigned short As[128 * 32];
    __shared__ unsigned short Bs[128 * 32];
    int tid = threadIdx.x;
    int wave = tid >> 6, lane = tid & 63;
    int q = lane >> 4, l16 = lane & 15;
    int row0 = blockIdx.x * 128;

    v4f acc[2][8];
#pragma unroll
    for (int m = 0; m < 2; m++)
#pragma unroll
        for (int n = 0; n < 8; n++) acc[m][n] = (v4f){0.f, 0.f, 0.f, 0.f};

    for (int kc = 0; kc < 8; kc++) {
        const unsigned short* Ag = (kc < 4) ? xa : xr;
        const unsigned short* Bg = (kc < 4) ? wl : wr;
        int koff = (kc & 3) * 32;
#pragma unroll
        for (int it = 0; it < 2; it++) {
            int seg = tid + it * 256;  // 0..511 : 128 rows x 4 segments of 8 bf16
            int r = seg >> 2, sg = seg & 3;
            int gr = row0 + r;
            if (gr > NN - 1) gr = NN - 1;
            v8s a = *(const v8s*)(Ag + (size_t)gr * HID + koff + sg * 8);
            *(v8s*)(As + r * 32 + sg * 8) = a;
            v8s b = *(const v8s*)(Bg + (size_t)r * HID + koff + sg * 8);
            *(v8s*)(Bs + r * 32 + sg * 8) = b;
        }
        __syncthreads();
        v8s a0 = *(const v8s*)(As + (wave * 32 + l16) * 32 + q * 8);
        v8s a1 = *(const v8s*)(As + (wave * 32 + 16 + l16) * 32 + q * 8);
#pragma unroll
        for (int nt = 0; nt < 8; nt++) {
            v8s b = *(const v8s*)(Bs + (nt * 16 + l16) * 32 + q * 8);
            acc[0][nt] = __builtin_amdgcn_mfma_f32_16x16x32_bf16(a0, b, acc[0][nt], 0, 0, 0);
            acc[1][nt] = __builtin_amdgcn_mfma_f32_16x16x32_bf16(a1, b, acc[1][nt], 0, 0, 0);
        }
        __syncthreads();
    }
#pragma unroll
    for (int nt = 0; nt < 8; nt++) {
        int col = nt * 16 + l16;
        float bv = bias[col];
#pragma unroll
        for (int mt = 0; mt < 2; mt++) {
#pragma unroll
            for (int r = 0; r < 4; r++) {
                int row = row0 + wave * 32 + mt * 16 + q * 4 + r;
                if (row < NN) {
                    float v = acc[mt][nt][r] + bv;
                    v = v > 0.f ? v : 0.f;
                    out[(size_t)row * HID + col] = f2bf(v);
                }
            }
        }
    }
}

// ---------- global mean pool (batch sorted) ----------
__global__ __launch_bounds__(128) void k_pool(const unsigned short* __restrict__ x2,
                                              const int* __restrict__ batch,
                                              float* __restrict__ gsum,
                                              float* __restrict__ gcnt) {
    int tid = threadIdx.x;
    int start = blockIdx.x * 128;
    int end = start + 128;
    if (end > NN) end = NN;
    int cur = batch[start];
    float acc = 0.f;
    int cnt = 0;
    for (int n = start; n < end; n++) {
        int b = batch[n];  // uniform across block
        if (b != cur) {
            atomicAdd(&gsum[cur * HID + tid], acc);
            if (tid == 0) atomicAdd(&gcnt[cur], (float)cnt);
            acc = 0.f;
            cnt = 0;
            cur = b;
        }
        acc += __uint_as_float(((unsigned)x2[(size_t)n * HID + tid]) << 16);
        cnt++;
    }
    atomicAdd(&gsum[cur * HID + tid], acc);
    if (tid == 0) atomicAdd(&gcnt[cur], (float)cnt);
}

// ---------- final classifier ----------
__global__ __launch_bounds__(128) void k_final(const float* __restrict__ gsum,
                                               const float* __restrict__ gcnt,
                                               const float* __restrict__ w_out,
                                               const float* __restrict__ b_out,
                                               float* __restrict__ out) {
    __shared__ float mean[HID];
    int g = blockIdx.x, tid = threadIdx.x;
    float c = gcnt[g];
    float ic = 1.0f / fmaxf(c, 1.0f);
    mean[tid] = gsum[g * HID + tid] * ic;
    __syncthreads();
    if (tid < NC) {
        float s = b_out[tid];
#pragma unroll 16
        for (int d = 0; d < HID; d++) s += mean[d] * w_out[tid * HID + d];
        out[g * NC + tid] = s;
    }
}

extern "C" void kernel_launch(void* const* d_in, const int* in_sizes, int n_in,
                              void* d_out, int out_size, void* d_ws, size_t ws_size,
                              hipStream_t stream) {
    const int* x_tokens = (const int*)d_in[0];
    const int* edge = (const int*)d_in[1];
    const int* batch = (const int*)d_in[2];
    const float* emb_table = (const float*)d_in[3];
    const float* w1l = (const float*)d_in[4];
    const float* b1 = (const float*)d_in[5];
    const float* w1r = (const float*)d_in[6];
    const float* w2l = (const float*)d_in[7];
    const float* b2 = (const float*)d_in[8];
    const float* w2r = (const float*)d_in[9];
    const float* w_out = (const float*)d_in[10];
    const float* b_out = (const float*)d_in[11];
    float* out = (float*)d_out;

    char* ws = (char*)d_ws;
    size_t off = 0;
    auto alloc = [&](size_t bytes) {
        void* p = ws + off;
        off += (bytes + 255) & ~(size_t)255;
        return p;
    };
    int* counts = (int*)alloc(NN * 4);
    int* row_ptr = (int*)alloc((NN + 1) * 4);
    int* cursor = (int*)alloc(NN * 4);
    int* csr_src = (int*)alloc(NE * 4);
    int* bsum = (int*)alloc(NBLK * 4);
    unsigned short* wbf = (unsigned short*)alloc(4 * HID * EMB * 2);
    float* gsum = (float*)alloc(NG * HID * 4);
    float* gcnt = (float*)alloc(NG * 4);
    unsigned short* x0 = (unsigned short*)alloc((size_t)NN * EMB * 2);
    unsigned short* x1 = (unsigned short*)alloc((size_t)NN * HID * 2);
    unsigned short* aggr = (unsigned short*)alloc((size_t)NN * HID * 2);
    unsigned short* x2 = x0;        // x0 dead after layer-1 GEMM; reuse
    unsigned short* table_bf = x1;  // x1 dead until layer-1 GEMM writes it; reuse

    const int* srcp = edge;
    const int* dstp = edge + NE;

    k_conv<<<(TPAIRS + WPAIRS + 255) / 256, 256, 0, stream>>>(
        emb_table, table_bf, w1l, w1r, w2l, w2r, wbf, counts, gsum, gcnt);
    k_count<<<(NE + 255) / 256, 256, 0, stream>>>(dstp, counts);
    k_bsum<<<NBLK, 256, 0, stream>>>(counts, bsum);
    k_scan2<<<NBLK, 256, 0, stream>>>(counts, bsum, row_ptr, cursor);
    k_scatter<<<(NE + 255) / 256, 256, 0, stream>>>(srcp, dstp, cursor, csr_src);
    k_embed<<<(NN + 3) / 4, 256, 0, stream>>>(x_tokens, table_bf, x0);
    k_aggr<<<(NN + 3) / 4, 256, 0, stream>>>(x0, row_ptr, csr_src, aggr);
    k_sage<<<(NN + 127) / 128, 256, 0, stream>>>(aggr, x0, wbf, wbf + 16384, b1, x1);
    k_aggr<<<(NN + 3) / 4, 256, 0, stream>>>(x1, row_ptr, csr_src, aggr);
    k_sage<<<(NN + 127) / 128, 256, 0, stream>>>(aggr, x1, wbf + 32768, wbf + 49152, b2, x2);
    k_pool<<<(NN + 127) / 128, 128, 0, stream>>>(x2, batch, gsum, gcnt);
    k_final<<<NG, 128, 0, stream>>>(gsum, gcnt, w_out, b_out, out);
}

// Round 5
// 283.396 us; speedup vs baseline: 1.7371x; 1.0225x over previous
//
#include <hip/hip_runtime.h>
#include <hip/hip_bf16.h>

#define NN 50000
#define NE 600000
#define BAG 16
#define EMB 128
#define HID 128
#define NC 10
#define NG 512
#define PAD_IDX 1
#define VOCAB 10000
#define NBLK ((NN + 255) / 256)   // 196 scan blocks
#define TPAIRS (VOCAB * EMB / 2)  // 640k bf16 pairs in the table
#define WPAIRS (4 * HID * EMB / 2)
#define SCBLK ((NE + 255) / 256)  // scatter blocks in fused kernel
#define EMBLK ((NN + 3) / 4)      // embed blocks in fused kernel

typedef __attribute__((ext_vector_type(8))) short v8s;
typedef __attribute__((ext_vector_type(4))) float v4f;

__device__ __forceinline__ float bflo(unsigned u) { return __uint_as_float(u << 16); }
__device__ __forceinline__ float bfhi(unsigned u) { return __uint_as_float(u & 0xffff0000u); }
__device__ __forceinline__ unsigned short f2bf(float f) {
    unsigned u = __float_as_uint(f);
    return (unsigned short)((u + 0x7fffu + ((u >> 16) & 1u)) >> 16);
}
__device__ __forceinline__ void acc8(float* a, v8s v) {
    unsigned* u = (unsigned*)&v;
#pragma unroll
    for (int j = 0; j < 4; j++) {
        a[2 * j] += bflo(u[j]);
        a[2 * j + 1] += bfhi(u[j]);
    }
}

// ---------- CSR build ----------
__global__ void k_count(const int* __restrict__ dst, int* __restrict__ counts) {
    int e = blockIdx.x * blockDim.x + threadIdx.x;
    if (e < NE) atomicAdd(&counts[dst[e]], 1);
}

__global__ __launch_bounds__(256) void k_bsum(const int* __restrict__ counts,
                                              int* __restrict__ bsum) {
    int blk = blockIdx.x;
    int i = blk * 256 + threadIdx.x;
    int v = (i < NN) ? counts[i] : 0;
#pragma unroll
    for (int off = 32; off; off >>= 1) v += __shfl_down(v, off, 64);
    __shared__ int ws4[4];
    if ((threadIdx.x & 63) == 0) ws4[threadIdx.x >> 6] = v;
    __syncthreads();
    if (threadIdx.x == 0) bsum[blk] = ws4[0] + ws4[1] + ws4[2] + ws4[3];
}

// block offset = reduce(bsum[0..blk)), then intra-block scan
__global__ __launch_bounds__(256) void k_scan2(const int* __restrict__ counts,
                                               const int* __restrict__ bsum,
                                               int* __restrict__ row_ptr,
                                               int* __restrict__ cursor) {
    __shared__ int buf[256];
    __shared__ int off_s;
    int blk = blockIdx.x, tid = threadIdx.x;
    int bv = (tid < blk) ? bsum[tid] : 0;  // NBLK=196 <= 256
#pragma unroll
    for (int off = 32; off; off >>= 1) bv += __shfl_down(bv, off, 64);
    __shared__ int ws4[4];
    if ((tid & 63) == 0) ws4[tid >> 6] = bv;
    __syncthreads();
    if (tid == 0) off_s = ws4[0] + ws4[1] + ws4[2] + ws4[3];
    int i = blk * 256 + tid;
    int v = (i < NN) ? counts[i] : 0;
    buf[tid] = v;
    __syncthreads();
    for (int off = 1; off < 256; off <<= 1) {
        int t = (tid >= off) ? buf[tid - off] : 0;
        __syncthreads();
        buf[tid] += t;
        __syncthreads();
    }
    if (i < NN) {
        int ex = off_s + buf[tid] - v;
        row_ptr[i] = ex;
        cursor[i] = ex;
    }
    if (i == 0) row_ptr[NN] = NE;
}

// ---------- fp32->bf16 conversion (table + weights) and workspace zeroing ----------
__global__ void k_conv(const float* __restrict__ t, unsigned short* __restrict__ tb,
                       const float* __restrict__ w1l, const float* __restrict__ w1r,
                       const float* __restrict__ w2l, const float* __restrict__ w2r,
                       unsigned short* __restrict__ wbf, int* __restrict__ counts,
                       float* __restrict__ gsum, float* __restrict__ gcnt) {
    int i = blockIdx.x * blockDim.x + threadIdx.x;  // pair index
    if (i < NN) counts[i] = 0;
    if (i < NG * HID) gsum[i] = 0.f;
    if (i < NG) gcnt[i] = 0.f;
    if (i < TPAIRS) {
        float2 v = *(const float2*)(t + (size_t)i * 2);
        unsigned lo = f2bf(v.x), hi = f2bf(v.y);
        *(unsigned*)(tb + (size_t)i * 2) = lo | (hi << 16);
    } else {
        int j = i - TPAIRS;
        if (j >= WPAIRS) return;
        int k = j * 2;      // element index in concatenated [w1l|w1r|w2l|w2r]
        int arr = k >> 14;  // 16384 elements per matrix
        int o = k & 16383;
        const float* w = (arr == 0) ? w1l : (arr == 1) ? w1r : (arr == 2) ? w2l : w2r;
        float2 v = *(const float2*)(w + o);
        unsigned lo = f2bf(v.x), hi = f2bf(v.y);
        *(unsigned*)(wbf + k) = lo | (hi << 16);
    }
}

// ---------- fused: CSR scatter (blocks 0..SCBLK) + embedding-bag mean (rest) ----------
// Embed: one wave/node; 16 lanes span a 256B row -> one dwordx4 wave-load = 4 rows.
// PAD row of the table is exactly zero -> sum unconditionally, mask only the count.
__global__ __launch_bounds__(256) void k_scatem(const int* __restrict__ src,
                                                const int* __restrict__ dst,
                                                int* __restrict__ cursor,
                                                int* __restrict__ csr_src,
                                                const int* __restrict__ tokens,
                                                const unsigned short* __restrict__ table,
                                                unsigned short* __restrict__ x0) {
    int b = blockIdx.x;
    if (b < SCBLK) {
        int e = b * 256 + threadIdx.x;
        if (e < NE) {
            int sv = src[e];
            int p = atomicAdd(&cursor[dst[e]], 1);
            csr_src[p] = sv;
        }
        return;
    }
    b -= SCBLK;
    int node = b * 4 + (threadIdx.x >> 6);
    int lane = threadIdx.x & 63;
    if (node >= NN) return;
    const int* tp = tokens + node * BAG;
    int g = lane >> 4;   // which of 4 rows this lane helps gather
    int sl = lane & 15;  // 16B slice within the row
    int tok_l = tp[sl];  // bag token at position (lane&15), replicated 4x
    unsigned long long m = __ballot(tok_l != PAD_IDX);
    int cnt = __popcll(m & 0xFFFFull);
    float a[8];
#pragma unroll
    for (int j = 0; j < 8; j++) a[j] = 0.f;
#pragma unroll
    for (int it = 0; it < 4; it++) {
        int tok = __shfl(tok_l, it * 4 + g, 64);
        v8s v = *(const v8s*)(table + (size_t)tok * EMB + sl * 8);
        acc8(a, v);
    }
#pragma unroll
    for (int j = 0; j < 8; j++) {
        a[j] += __shfl_xor(a[j], 16, 64);
        a[j] += __shfl_xor(a[j], 32, 64);
    }
    float inv = 1.0f / (float)(cnt > 0 ? cnt : 1);
    if (g == 0) {
        uint4 o;
        o.x = f2bf(a[0] * inv) | ((unsigned)f2bf(a[1] * inv) << 16);
        o.y = f2bf(a[2] * inv) | ((unsigned)f2bf(a[3] * inv) << 16);
        o.z = f2bf(a[4] * inv) | ((unsigned)f2bf(a[5] * inv) << 16);
        o.w = f2bf(a[6] * inv) | ((unsigned)f2bf(a[7] * inv) << 16);
        *(uint4*)(x0 + (size_t)node * EMB + sl * 8) = o;
    }
}

// ---------- neighbor mean aggregation ----------
// One wave/node. All <=64 CSR indices loaded lane-parallel in ONE load, then
// broadcast via shfl: the gather loop has NO index loads -> pure MLP gathers.
__global__ __launch_bounds__(256) void k_aggr(const unsigned short* __restrict__ x,
                                              const int* __restrict__ row_ptr,
                                              const int* __restrict__ csr_src,
                                              unsigned short* __restrict__ aggr) {
    int node = blockIdx.x * 4 + (threadIdx.x >> 6);
    int lane = threadIdx.x & 63;
    if (node >= NN) return;
    int s = row_ptr[node], e = row_ptr[node + 1];
    int g = lane >> 4, sl = lane & 15;
    float a[8];
#pragma unroll
    for (int j = 0; j < 8; j++) a[j] = 0.f;
    for (int base = s; base < e; base += 64) {
        int m = e - base;
        if (m > 64) m = 64;
        int idx_l = csr_src[base + ((lane < m) ? lane : 0)];  // one lane-parallel load
        int i = 0;
        for (; i + 8 <= m; i += 8) {  // 2 KB in flight, no index loads
            int t0 = __shfl(idx_l, i + g, 64);
            int t1 = __shfl(idx_l, i + 4 + g, 64);
            v8s v0 = *(const v8s*)(x + (size_t)t0 * HID + sl * 8);
            v8s v1 = *(const v8s*)(x + (size_t)t1 * HID + sl * 8);
            acc8(a, v0);
            acc8(a, v1);
        }
        for (; i + 4 <= m; i += 4) {
            int t0 = __shfl(idx_l, i + g, 64);
            v8s v0 = *(const v8s*)(x + (size_t)t0 * HID + sl * 8);
            acc8(a, v0);
        }
        int rem = m - i;  // 0..3
        if (rem > 0) {
            int t0 = __shfl(idx_l, (g < rem) ? i + g : i, 64);
            v8s v0 = *(const v8s*)(x + (size_t)t0 * HID + sl * 8);
            if (g < rem) acc8(a, v0);
        }
    }
#pragma unroll
    for (int j = 0; j < 8; j++) {
        a[j] += __shfl_xor(a[j], 16, 64);
        a[j] += __shfl_xor(a[j], 32, 64);
    }
    int deg = e - s;
    float inv = 1.0f / (float)(deg > 0 ? deg : 1);
    if (g == 0) {
        uint4 o;
        o.x = f2bf(a[0] * inv) | ((unsigned)f2bf(a[1] * inv) << 16);
        o.y = f2bf(a[2] * inv) | ((unsigned)f2bf(a[3] * inv) << 16);
        o.z = f2bf(a[4] * inv) | ((unsigned)f2bf(a[5] * inv) << 16);
        o.w = f2bf(a[6] * inv) | ((unsigned)f2bf(a[7] * inv) << 16);
        *(uint4*)(aggr + (size_t)node * HID + sl * 8) = o;
    }
}

// ---------- fused SAGE linear: relu(aggr@wl^T + b + x@wr^T), MFMA bf16 ----------
__global__ __launch_bounds__(256) void k_sage(const unsigned short* __restrict__ xa,
                                              const unsigned short* __restrict__ xr,
                                              const unsigned short* __restrict__ wl,
                                              const unsigned short* __restrict__ wr,
                                              const float* __restrict__ bias,
                                              unsigned short* __restrict__ out) {
    __shared__ unsigned short As[128 * 32];
    __shared__ unsigned short Bs[128 * 32];
    int tid = threadIdx.x;
    int wave = tid >> 6, lane = tid & 63;
    int q = lane >> 4, l16 = lane & 15;
    int row0 = blockIdx.x * 128;

    v4f acc[2][8];
#pragma unroll
    for (int m = 0; m < 2; m++)
#pragma unroll
        for (int n = 0; n < 8; n++) acc[m][n] = (v4f){0.f, 0.f, 0.f, 0.f};

    for (int kc = 0; kc < 8; kc++) {
        const unsigned short* Ag = (kc < 4) ? xa : xr;
        const unsigned short* Bg = (kc < 4) ? wl : wr;
        int koff = (kc & 3) * 32;
#pragma unroll
        for (int it = 0; it < 2; it++) {
            int seg = tid + it * 256;  // 0..511 : 128 rows x 4 segments of 8 bf16
            int r = seg >> 2, sg = seg & 3;
            int gr = row0 + r;
            if (gr > NN - 1) gr = NN - 1;
            v8s a = *(const v8s*)(Ag + (size_t)gr * HID + koff + sg * 8);
            *(v8s*)(As + r * 32 + sg * 8) = a;
            v8s b = *(const v8s*)(Bg + (size_t)r * HID + koff + sg * 8);
            *(v8s*)(Bs + r * 32 + sg * 8) = b;
        }
        __syncthreads();
        v8s a0 = *(const v8s*)(As + (wave * 32 + l16) * 32 + q * 8);
        v8s a1 = *(const v8s*)(As + (wave * 32 + 16 + l16) * 32 + q * 8);
#pragma unroll
        for (int nt = 0; nt < 8; nt++) {
            v8s b = *(const v8s*)(Bs + (nt * 16 + l16) * 32 + q * 8);
            acc[0][nt] = __builtin_amdgcn_mfma_f32_16x16x32_bf16(a0, b, acc[0][nt], 0, 0, 0);
            acc[1][nt] = __builtin_amdgcn_mfma_f32_16x16x32_bf16(a1, b, acc[1][nt], 0, 0, 0);
        }
        __syncthreads();
    }
#pragma unroll
    for (int nt = 0; nt < 8; nt++) {
        int col = nt * 16 + l16;
        float bv = bias[col];
#pragma unroll
        for (int mt = 0; mt < 2; mt++) {
#pragma unroll
            for (int r = 0; r < 4; r++) {
                int row = row0 + wave * 32 + mt * 16 + q * 4 + r;
                if (row < NN) {
                    float v = acc[mt][nt][r] + bv;
                    v = v > 0.f ? v : 0.f;
                    out[(size_t)row * HID + col] = f2bf(v);
                }
            }
        }
    }
}

// ---------- global mean pool (batch sorted) ----------
__global__ __launch_bounds__(128) void k_pool(const unsigned short* __restrict__ x2,
                                              const int* __restrict__ batch,
                                              float* __restrict__ gsum,
                                              float* __restrict__ gcnt) {
    int tid = threadIdx.x;
    int start = blockIdx.x * 128;
    int end = start + 128;
    if (end > NN) end = NN;
    int cur = batch[start];
    float acc = 0.f;
    int cnt = 0;
    for (int n = start; n < end; n++) {
        int b = batch[n];  // uniform across block
        if (b != cur) {
            atomicAdd(&gsum[cur * HID + tid], acc);
            if (tid == 0) atomicAdd(&gcnt[cur], (float)cnt);
            acc = 0.f;
            cnt = 0;
            cur = b;
        }
        acc += __uint_as_float(((unsigned)x2[(size_t)n * HID + tid]) << 16);
        cnt++;
    }
    atomicAdd(&gsum[cur * HID + tid], acc);
    if (tid == 0) atomicAdd(&gcnt[cur], (float)cnt);
}

// ---------- final classifier ----------
__global__ __launch_bounds__(128) void k_final(const float* __restrict__ gsum,
                                               const float* __restrict__ gcnt,
                                               const float* __restrict__ w_out,
                                               const float* __restrict__ b_out,
                                               float* __restrict__ out) {
    __shared__ float mean[HID];
    int g = blockIdx.x, tid = threadIdx.x;
    float c = gcnt[g];
    float ic = 1.0f / fmaxf(c, 1.0f);
    mean[tid] = gsum[g * HID + tid] * ic;
    __syncthreads();
    if (tid < NC) {
        float s = b_out[tid];
#pragma unroll 16
        for (int d = 0; d < HID; d++) s += mean[d] * w_out[tid * HID + d];
        out[g * NC + tid] = s;
    }
}

extern "C" void kernel_launch(void* const* d_in, const int* in_sizes, int n_in,
                              void* d_out, int out_size, void* d_ws, size_t ws_size,
                              hipStream_t stream) {
    const int* x_tokens = (const int*)d_in[0];
    const int* edge = (const int*)d_in[1];
    const int* batch = (const int*)d_in[2];
    const float* emb_table = (const float*)d_in[3];
    const float* w1l = (const float*)d_in[4];
    const float* b1 = (const float*)d_in[5];
    const float* w1r = (const float*)d_in[6];
    const float* w2l = (const float*)d_in[7];
    const float* b2 = (const float*)d_in[8];
    const float* w2r = (const float*)d_in[9];
    const float* w_out = (const float*)d_in[10];
    const float* b_out = (const float*)d_in[11];
    float* out = (float*)d_out;

    char* ws = (char*)d_ws;
    size_t off = 0;
    auto alloc = [&](size_t bytes) {
        void* p = ws + off;
        off += (bytes + 255) & ~(size_t)255;
        return p;
    };
    int* counts = (int*)alloc(NN * 4);
    int* row_ptr = (int*)alloc((NN + 1) * 4);
    int* cursor = (int*)alloc(NN * 4);
    int* csr_src = (int*)alloc(NE * 4);
    int* bsum = (int*)alloc(NBLK * 4);
    unsigned short* wbf = (unsigned short*)alloc(4 * HID * EMB * 2);
    float* gsum = (float*)alloc(NG * HID * 4);
    float* gcnt = (float*)alloc(NG * 4);
    unsigned short* x0 = (unsigned short*)alloc((size_t)NN * EMB * 2);
    unsigned short* x1 = (unsigned short*)alloc((size_t)NN * HID * 2);
    unsigned short* aggr = (unsigned short*)alloc((size_t)NN * HID * 2);
    unsigned short* x2 = x0;        // x0 dead after layer-1 GEMM; reuse
    unsigned short* table_bf = x1;  // x1 dead until layer-1 GEMM writes it; reuse

    const int* srcp = edge;
    const int* dstp = edge + NE;

    k_conv<<<(TPAIRS + WPAIRS + 255) / 256, 256, 0, stream>>>(
        emb_table, table_bf, w1l, w1r, w2l, w2r, wbf, counts, gsum, gcnt);
    k_count<<<(NE + 255) / 256, 256, 0, stream>>>(dstp, counts);
    k_bsum<<<NBLK, 256, 0, stream>>>(counts, bsum);
    k_scan2<<<NBLK, 256, 0, stream>>>(counts, bsum, row_ptr, cursor);
    k_scatem<<<SCBLK + EMBLK, 256, 0, stream>>>(srcp, dstp, cursor, csr_src,
                                                x_tokens, table_bf, x0);
    k_aggr<<<(NN + 3) / 4, 256, 0, stream>>>(x0, row_ptr, csr_src, aggr);
    k_sage<<<(NN + 127) / 128, 256, 0, stream>>>(aggr, x0, wbf, wbf + 16384, b1, x1);
    k_aggr<<<(NN + 3) / 4, 256, 0, stream>>>(x1, row_ptr, csr_src, aggr);
    k_sage<<<(NN + 127) / 128, 256, 0, stream>>>(aggr, x1, wbf + 32768, wbf + 49152, b2, x2);
    k_pool<<<(NN + 127) / 128, 128, 0, stream>>>(x2, batch, gsum, gcnt);
    k_final<<<NG, 128, 0, stream>>>(gsum, gcnt, w_out, b_out, out);
}